// Round 1
// baseline (559.923 us; speedup 1.0000x reference)
//
#include <hip/hip_runtime.h>

// L2LGD2: learned-optimizer update step.
//   per row i of N=8.4M:
//     g_in = preprocess(g[i])                      (2 features)
//     r,z,n = GRUCell(g_in, h[i,0:8])              (8x8 hidden matmuls)
//     h_new = (1-z)*n + z*h
//     out   = -exp(h_new @ Wm + bm) * g[i]
// Layout: 8 lanes per row; lane j holds column j of every weight matrix
// (~35 weight VGPRs/lane). h loads/stores are fully coalesced (h_flat[tid]).
// Cross-lane h broadcast + final reduction via ds_swizzle (DS pipe, no LDS
// allocation, broadcast patterns are bank-conflict-free).

#define SWZ(x, imm) __int_as_float(__builtin_amdgcn_ds_swizzle(__float_as_int(x), (imm)))

__global__ __launch_bounds__(256) void gru_l2l_kernel(
    const float* __restrict__ hp, const float* __restrict__ gp,
    const float* __restrict__ Wi_r, const float* __restrict__ Wh_r, const float* __restrict__ bh_r,
    const float* __restrict__ Wi_z, const float* __restrict__ Wh_z, const float* __restrict__ bh_z,
    const float* __restrict__ Wi_n, const float* __restrict__ Wh_n, const float* __restrict__ bh_n,
    const float* __restrict__ Wm, const float* __restrict__ bm,
    float* __restrict__ out, int nrows)
{
    const int tot    = nrows << 3;
    const int tid    = blockIdx.x * blockDim.x + threadIdx.x;
    const int stride = blockDim.x * gridDim.x;   // multiple of 8 -> j is loop-invariant
    const int j      = tid & 7;                  // hidden unit owned by this lane

    // Per-lane weights: column j of each matrix. Wi_* is [2,8] row-major,
    // Wh_* is [8,8] row-major, Wm is [8,1].
    const float wir0 = Wi_r[j], wir1 = Wi_r[8 + j];
    const float wiz0 = Wi_z[j], wiz1 = Wi_z[8 + j];
    const float win0 = Wi_n[j], win1 = Wi_n[8 + j];
    float whr[8], whz[8], whn[8];
#pragma unroll
    for (int k = 0; k < 8; ++k) {
        whr[k] = Wh_r[k * 8 + j];
        whz[k] = Wh_z[k * 8 + j];
        whn[k] = Wh_n[k * 8 + j];
    }
    const float br  = bh_r[j], bz = bh_z[j], bn = bh_n[j];
    const float wm  = Wm[j];
    const float bmv = bm[0];
    float* __restrict__ outo = out + tot;        // out scalar region follows h_new

    for (int i = tid; i < tot; i += stride) {
        const int   row  = i >> 3;
        const float hval = hp[i];                // coalesced: h_flat[tid]
        const float g    = gp[row];              // 8 lanes share each address

        // gradient preprocessing (branch is continuous at the boundary:
        // l = -1  <=>  exp(10)*|g| ~= 1, so fast-log branch flips are harmless)
        const float ag = fabsf(g) + 1e-8f;
        const float lg = __logf(ag) * 0.1f;
        float gin0, gin1;
        if (lg >= -1.0f) {
            gin0 = lg;
            gin1 = (g > 0.0f) ? 1.0f : -1.0f;    // g != 0 guaranteed in this branch
        } else {
            gin0 = -1.0f;
            gin1 = 22026.465794806718f * g;      // exp(10) * g
        }

        // broadcast the row's 8 h-values across its 8-lane group
        // ds_swizzle BitMode: src = ((lane & 0x18) | k) -> offset = (k<<5)|0x18
        const float hk0 = SWZ(hval, 0x018), hk1 = SWZ(hval, 0x038);
        const float hk2 = SWZ(hval, 0x058), hk3 = SWZ(hval, 0x078);
        const float hk4 = SWZ(hval, 0x098), hk5 = SWZ(hval, 0x0B8);
        const float hk6 = SWZ(hval, 0x0D8), hk7 = SWZ(hval, 0x0F8);

        float ar = fmaf(gin0, wir0, fmaf(gin1, wir1, br));
        float az = fmaf(gin0, wiz0, fmaf(gin1, wiz1, bz));
        float an = fmaf(gin0, win0, gin1 * win1);  // input dense: no bias
        float hn = bn;
#define DOT3(K) \
        ar = fmaf(hk##K, whr[K], ar); \
        az = fmaf(hk##K, whz[K], az); \
        hn = fmaf(hk##K, whn[K], hn);
        DOT3(0) DOT3(1) DOT3(2) DOT3(3) DOT3(4) DOT3(5) DOT3(6) DOT3(7)
#undef DOT3

        const float r   = __builtin_amdgcn_rcpf(1.0f + __expf(-ar));  // sigmoid
        const float z   = __builtin_amdgcn_rcpf(1.0f + __expf(-az));
        const float pre = fmaf(r, hn, an);
        // overflow-safe tanh: exp(-2|x|) in [0,1]
        const float t    = __expf(-2.0f * fabsf(pre));
        const float nval = copysignf((1.0f - t) * __builtin_amdgcn_rcpf(1.0f + t), pre);
        const float hnew = fmaf(z, hval - nval, nval);  // (1-z)*n + z*h
        out[i] = hnew;                                  // coalesced

        // Dense(1): reduce hnew*wm across the 8-lane group (xor butterfly)
        float s = hnew * wm;
        s += SWZ(s, 0x041F);   // xor 1
        s += SWZ(s, 0x081F);   // xor 2
        s += SWZ(s, 0x101F);   // xor 4
        if (j == 0) {
            outo[row] = -__expf(s + bmv) * g;
        }
    }
}

extern "C" void kernel_launch(void* const* d_in, const int* in_sizes, int n_in,
                              void* d_out, int out_size, void* d_ws, size_t ws_size,
                              hipStream_t stream) {
    const float* hp   = (const float*)d_in[0];
    const float* gp   = (const float*)d_in[1];
    const float* Wi_r = (const float*)d_in[2];
    const float* Wh_r = (const float*)d_in[3];
    const float* bh_r = (const float*)d_in[4];
    const float* Wi_z = (const float*)d_in[5];
    const float* Wh_z = (const float*)d_in[6];
    const float* bh_z = (const float*)d_in[7];
    const float* Wi_n = (const float*)d_in[8];
    const float* Wh_n = (const float*)d_in[9];
    const float* bh_n = (const float*)d_in[10];
    const float* Wm   = (const float*)d_in[11];
    const float* bm   = (const float*)d_in[12];
    const int nrows   = in_sizes[1];             // N = 8388608

    gru_l2l_kernel<<<8192, 256, 0, stream>>>(hp, gp, Wi_r, Wh_r, bh_r,
                                             Wi_z, Wh_z, bh_z,
                                             Wi_n, Wh_n, bh_n,
                                             Wm, bm, (float*)d_out, nrows);
}

// Round 2
// 553.650 us; speedup vs baseline: 1.0113x; 1.0113x over previous
//
#include <hip/hip_runtime.h>

// L2LGD2: learned-optimizer update step (GRUCell hid=8 + Dense(1) per row).
// Layout: 8 lanes per row; lane j owns column j of every weight matrix.
// h loads/stores fully coalesced; cross-lane h broadcast + Dense(1) reduction
// via ds_swizzle (broadcast patterns, conflict-free, no LDS allocation).
//
// R2 fix: round-1 showed VGPR_Count=28 -> compiler sank the ~35 loop-invariant
// weight loads INTO the loop (3x VALU blowup, dur 206us at VALUBusy 82%).
// PIN() forces each weight into a VGPR via an opaque inline-asm result the
// compiler cannot rematerialize. r/z-gate weights pre-scaled by log2(e) so the
// sigmoids use raw v_exp_f32 (exp2) with no inner multiply.

#define SWZ(x, imm) __int_as_float(__builtin_amdgcn_ds_swizzle(__float_as_int(x), (imm)))
#define PIN(x) asm volatile("" : "+v"(x))

__global__ __launch_bounds__(256) void gru_l2l_kernel(
    const float* __restrict__ hp, const float* __restrict__ gp,
    const float* __restrict__ Wi_r, const float* __restrict__ Wh_r, const float* __restrict__ bh_r,
    const float* __restrict__ Wi_z, const float* __restrict__ Wh_z, const float* __restrict__ bh_z,
    const float* __restrict__ Wi_n, const float* __restrict__ Wh_n, const float* __restrict__ bh_n,
    const float* __restrict__ Wm, const float* __restrict__ bm,
    float* __restrict__ out, int nrows)
{
    const int tot    = nrows << 3;
    const int tid    = blockIdx.x * blockDim.x + threadIdx.x;
    const int stride = blockDim.x * gridDim.x;   // multiple of 8 -> j loop-invariant
    const int j      = tid & 7;                  // hidden unit owned by this lane

    const float L2E = 1.44269504088896341f;      // log2(e)

    // Per-lane weights: column j. Wi_* is [2,8], Wh_* [8,8] row-major, Wm [8,1].
    // r/z weights+biases pre-scaled by log2e: sigmoid(x) = rcp(1 + exp2(-x*log2e)).
    float wir0 = Wi_r[j] * L2E, wir1 = Wi_r[8 + j] * L2E;
    float wiz0 = Wi_z[j] * L2E, wiz1 = Wi_z[8 + j] * L2E;
    float win0 = Wi_n[j],       win1 = Wi_n[8 + j];
    float whr[8], whz[8], whn[8];
#pragma unroll
    for (int k = 0; k < 8; ++k) {
        whr[k] = Wh_r[k * 8 + j] * L2E;
        whz[k] = Wh_z[k * 8 + j] * L2E;
        whn[k] = Wh_n[k * 8 + j];
    }
    float br = bh_r[j] * L2E, bz = bh_z[j] * L2E, bn = bh_n[j];
    float wm  = Wm[j];
    float bmv = bm[0];

    // Pin all loop-invariants into VGPRs (opaque to remat/sinking).
    PIN(wir0); PIN(wir1); PIN(wiz0); PIN(wiz1); PIN(win0); PIN(win1);
#pragma unroll
    for (int k = 0; k < 8; ++k) { PIN(whr[k]); PIN(whz[k]); PIN(whn[k]); }
    PIN(br); PIN(bz); PIN(bn); PIN(wm); PIN(bmv);

    float* __restrict__ outo = out + tot;        // out scalar region follows h_new

    for (int i = tid; i < tot; i += stride) {
        const int   row  = i >> 3;
        const float hval = hp[i];                // coalesced: h_flat[tid]
        const float g    = gp[row];              // 8 lanes share each address

        // gradient preprocessing. lg = log(|g|+eps)/10 computed as log2*(ln2/10).
        // Branch is continuous at lg==-1 (exp(10)*|g|~=1) so fast-log flips are safe.
        const float ag = fabsf(g) + 1e-8f;
        const float lg = __builtin_amdgcn_logf(ag) * 0.069314718055994531f;
        float gin0, gin1;
        if (lg >= -1.0f) {
            gin0 = lg;
            gin1 = (g > 0.0f) ? 1.0f : -1.0f;    // g != 0 guaranteed in this branch
        } else {
            gin0 = -1.0f;
            gin1 = 22026.465794806718f * g;      // exp(10) * g
        }

        // broadcast the row's 8 h-values across its 8-lane group
        // BitMode: dst_lane reads ((lane & 0x18) | k) -> offset = (k<<5)|0x18
        const float hk0 = SWZ(hval, 0x018), hk1 = SWZ(hval, 0x038);
        const float hk2 = SWZ(hval, 0x058), hk3 = SWZ(hval, 0x078);
        const float hk4 = SWZ(hval, 0x098), hk5 = SWZ(hval, 0x0B8);
        const float hk6 = SWZ(hval, 0x0D8), hk7 = SWZ(hval, 0x0F8);

        float ar = fmaf(gin0, wir0, fmaf(gin1, wir1, br));   // pre-scaled by log2e
        float az = fmaf(gin0, wiz0, fmaf(gin1, wiz1, bz));
        float an = fmaf(gin0, win0, gin1 * win1);            // input dense: no bias
        float hn = bn;
#define DOT3(K) \
        ar = fmaf(hk##K, whr[K], ar); \
        az = fmaf(hk##K, whz[K], az); \
        hn = fmaf(hk##K, whn[K], hn);
        DOT3(0) DOT3(1) DOT3(2) DOT3(3) DOT3(4) DOT3(5) DOT3(6) DOT3(7)
#undef DOT3

        // sigmoid with pre-scaled input: 1/(1+exp2(-x))
        const float r = __builtin_amdgcn_rcpf(1.0f + __builtin_amdgcn_exp2f(-ar));
        const float z = __builtin_amdgcn_rcpf(1.0f + __builtin_amdgcn_exp2f(-az));
        const float pre = fmaf(r, hn, an);
        // overflow-safe tanh: t = exp2(-2*log2e*|x|) in [0,1]
        const float t    = __builtin_amdgcn_exp2f(-2.885390081777927f * fabsf(pre));
        const float nval = copysignf((1.0f - t) * __builtin_amdgcn_rcpf(1.0f + t), pre);
        const float hnew = fmaf(z, hval - nval, nval);       // (1-z)*n + z*h
        out[i] = hnew;                                       // coalesced

        // Dense(1): reduce hnew*wm across the 8-lane group (xor butterfly)
        float s = hnew * wm;
        s += SWZ(s, 0x041F);   // xor 1
        s += SWZ(s, 0x081F);   // xor 2
        s += SWZ(s, 0x101F);   // xor 4
        if (j == 0) {
            outo[row] = -__builtin_amdgcn_exp2f(fmaf(s, L2E, bmv * L2E)) * g;
        }
    }
}

extern "C" void kernel_launch(void* const* d_in, const int* in_sizes, int n_in,
                              void* d_out, int out_size, void* d_ws, size_t ws_size,
                              hipStream_t stream) {
    const float* hp   = (const float*)d_in[0];
    const float* gp   = (const float*)d_in[1];
    const float* Wi_r = (const float*)d_in[2];
    const float* Wh_r = (const float*)d_in[3];
    const float* bh_r = (const float*)d_in[4];
    const float* Wi_z = (const float*)d_in[5];
    const float* Wh_z = (const float*)d_in[6];
    const float* bh_z = (const float*)d_in[7];
    const float* Wi_n = (const float*)d_in[8];
    const float* Wh_n = (const float*)d_in[9];
    const float* bh_n = (const float*)d_in[10];
    const float* Wm   = (const float*)d_in[11];
    const float* bm   = (const float*)d_in[12];
    const int nrows   = in_sizes[1];             // N = 8388608

    gru_l2l_kernel<<<8192, 256, 0, stream>>>(hp, gp, Wi_r, Wh_r, bh_r,
                                             Wi_z, Wh_z, bh_z,
                                             Wi_n, Wh_n, bh_n,
                                             Wm, bm, (float*)d_out, nrows);
}

// Round 3
// 550.306 us; speedup vs baseline: 1.0175x; 1.0061x over previous
//
#include <hip/hip_runtime.h>

// L2LGD2: learned-optimizer update step (GRUCell hid=8 + Dense(1) per row).
// Layout: 8 lanes per row; lane j owns column j of every weight matrix.
// h loads/stores fully coalesced; cross-lane h broadcast + Dense(1) reduction
// via ds_swizzle (broadcast patterns, conflict-free, no LDS allocation).
//
// R3 fix: R1/R2 showed VGPR_Count=28 -> the allocator sank/spilled the ~35
// loop-invariant weights to hit its max-occupancy pressure tier, paying ~35
// reloads + address math per iteration (~337 VALU cyc/iter vs ~168 ideal).
// Fix is two-part:
//   (a) __launch_bounds__(256, 4): min 4 waves/EU -> VGPR budget 128, so ~60
//       live values no longer trip the spill heuristic.
//   (b) asm volatile("" ::: "memory") after the weight loads: reloading
//       const memory past a potential-write barrier is illegal, so the
//       loaded values MUST stay register-resident across the loop.

#define SWZ(x, imm) __int_as_float(__builtin_amdgcn_ds_swizzle(__float_as_int(x), (imm)))
#define PIN(x) asm volatile("" : "+v"(x))

__global__ __launch_bounds__(256, 4) void gru_l2l_kernel(
    const float* __restrict__ hp, const float* __restrict__ gp,
    const float* __restrict__ Wi_r, const float* __restrict__ Wh_r, const float* __restrict__ bh_r,
    const float* __restrict__ Wi_z, const float* __restrict__ Wh_z, const float* __restrict__ bh_z,
    const float* __restrict__ Wi_n, const float* __restrict__ Wh_n, const float* __restrict__ bh_n,
    const float* __restrict__ Wm, const float* __restrict__ bm,
    float* __restrict__ out, int nrows)
{
    const int tot    = nrows << 3;
    const int tid    = blockIdx.x * blockDim.x + threadIdx.x;
    const int stride = blockDim.x * gridDim.x;   // multiple of 8 -> j loop-invariant
    const int j      = tid & 7;                  // hidden unit owned by this lane

    const float L2E = 1.44269504088896341f;      // log2(e)

    // Per-lane weights: column j. Wi_* is [2,8], Wh_* [8,8] row-major, Wm [8,1].
    // r/z weights+biases pre-scaled by log2e: sigmoid(x) = rcp(1 + exp2(-x*log2e)).
    float wir0 = Wi_r[j] * L2E, wir1 = Wi_r[8 + j] * L2E;
    float wiz0 = Wi_z[j] * L2E, wiz1 = Wi_z[8 + j] * L2E;
    float win0 = Wi_n[j],       win1 = Wi_n[8 + j];
    float whr[8], whz[8], whn[8];
#pragma unroll
    for (int k = 0; k < 8; ++k) {
        whr[k] = Wh_r[k * 8 + j] * L2E;
        whz[k] = Wh_z[k * 8 + j] * L2E;
        whn[k] = Wh_n[k * 8 + j];
    }
    float br = bh_r[j] * L2E, bz = bh_z[j] * L2E, bn = bh_n[j];
    float wm   = Wm[j];
    float bmv2 = bm[0] * L2E;                    // pre-scaled for final exp2

    // Pin every loop-invariant into a VGPR (opaque value, can't be resunk)...
    PIN(wir0); PIN(wir1); PIN(wiz0); PIN(wiz1); PIN(win0); PIN(win1);
#pragma unroll
    for (int k = 0; k < 8; ++k) { PIN(whr[k]); PIN(whz[k]); PIN(whn[k]); }
    PIN(br); PIN(bz); PIN(bn); PIN(wm); PIN(bmv2);
    // ...and forbid re-loading them: memory may be "modified" past this point.
    asm volatile("" ::: "memory");

    float* __restrict__ outo = out + tot;        // out scalar region follows h_new

    for (int i = tid; i < tot; i += stride) {
        const int   row  = i >> 3;
        const float hval = hp[i];                // coalesced: h_flat[tid]
        const float g    = gp[row];              // 8 lanes share each address

        // gradient preprocessing. lg = log(|g|+eps)/10 computed as log2*(ln2/10).
        // Branch is continuous at lg==-1 (exp(10)*|g|~=1) so fast-log flips are safe.
        const float ag = fabsf(g) + 1e-8f;
        const float lg = __builtin_amdgcn_logf(ag) * 0.069314718055994531f;
        float gin0, gin1;
        if (lg >= -1.0f) {
            gin0 = lg;
            gin1 = (g > 0.0f) ? 1.0f : -1.0f;    // g != 0 guaranteed in this branch
        } else {
            gin0 = -1.0f;
            gin1 = 22026.465794806718f * g;      // exp(10) * g
        }

        // broadcast the row's 8 h-values across its 8-lane group
        // BitMode: dst_lane reads ((lane & 0x18) | k) -> offset = (k<<5)|0x18
        const float hk0 = SWZ(hval, 0x018), hk1 = SWZ(hval, 0x038);
        const float hk2 = SWZ(hval, 0x058), hk3 = SWZ(hval, 0x078);
        const float hk4 = SWZ(hval, 0x098), hk5 = SWZ(hval, 0x0B8);
        const float hk6 = SWZ(hval, 0x0D8), hk7 = SWZ(hval, 0x0F8);

        float ar = fmaf(gin0, wir0, fmaf(gin1, wir1, br));   // pre-scaled by log2e
        float az = fmaf(gin0, wiz0, fmaf(gin1, wiz1, bz));
        float an = fmaf(gin0, win0, gin1 * win1);            // input dense: no bias
        float hn = bn;
#define DOT3(K) \
        ar = fmaf(hk##K, whr[K], ar); \
        az = fmaf(hk##K, whz[K], az); \
        hn = fmaf(hk##K, whn[K], hn);
        DOT3(0) DOT3(1) DOT3(2) DOT3(3) DOT3(4) DOT3(5) DOT3(6) DOT3(7)
#undef DOT3

        // sigmoid with pre-scaled input: 1/(1+exp2(-x))
        const float r = __builtin_amdgcn_rcpf(1.0f + __builtin_amdgcn_exp2f(-ar));
        const float z = __builtin_amdgcn_rcpf(1.0f + __builtin_amdgcn_exp2f(-az));
        const float pre = fmaf(r, hn, an);
        // overflow-safe tanh: t = exp2(-2*log2e*|x|) in [0,1]
        const float t    = __builtin_amdgcn_exp2f(-2.885390081777927f * fabsf(pre));
        const float nval = copysignf((1.0f - t) * __builtin_amdgcn_rcpf(1.0f + t), pre);
        const float hnew = fmaf(z, hval - nval, nval);       // (1-z)*n + z*h
        out[i] = hnew;                                       // coalesced

        // Dense(1): reduce hnew*wm across the 8-lane group (xor butterfly)
        float s = hnew * wm;
        s += SWZ(s, 0x041F);   // xor 1
        s += SWZ(s, 0x081F);   // xor 2
        s += SWZ(s, 0x101F);   // xor 4
        if (j == 0) {
            outo[row] = -__builtin_amdgcn_exp2f(fmaf(s, L2E, bmv2)) * g;
        }
    }
}

extern "C" void kernel_launch(void* const* d_in, const int* in_sizes, int n_in,
                              void* d_out, int out_size, void* d_ws, size_t ws_size,
                              hipStream_t stream) {
    const float* hp   = (const float*)d_in[0];
    const float* gp   = (const float*)d_in[1];
    const float* Wi_r = (const float*)d_in[2];
    const float* Wh_r = (const float*)d_in[3];
    const float* bh_r = (const float*)d_in[4];
    const float* Wi_z = (const float*)d_in[5];
    const float* Wh_z = (const float*)d_in[6];
    const float* bh_z = (const float*)d_in[7];
    const float* Wi_n = (const float*)d_in[8];
    const float* Wh_n = (const float*)d_in[9];
    const float* bh_n = (const float*)d_in[10];
    const float* Wm   = (const float*)d_in[11];
    const float* bm   = (const float*)d_in[12];
    const int nrows   = in_sizes[1];             // N = 8388608

    gru_l2l_kernel<<<8192, 256, 0, stream>>>(hp, gp, Wi_r, Wh_r, bh_r,
                                             Wi_z, Wh_z, bh_z,
                                             Wi_n, Wh_n, bh_n,
                                             Wm, bm, (float*)d_out, nrows);
}